// Round 5
// baseline (546.490 us; speedup 1.0000x reference)
//
#include <hip/hip_runtime.h>
#include <hip/hip_bf16.h>

#define NNODE 100000
#define CIN   64
#define CHID  64
#define NREL  8
#define KTOT  512      // NREL * CIN, flat k = r*64 + ki  (r = relation, ki = input channel)
#define NGRP  6250     // NNODE / 16

typedef __attribute__((ext_vector_type(8))) short bf16x8;
typedef __attribute__((ext_vector_type(4))) float f32x4;

__device__ __forceinline__ unsigned short f2bf(float f) {
    __hip_bfloat16 h = __float2bfloat16(f);
    return __builtin_bit_cast(unsigned short, h);
}
__device__ __forceinline__ float bf2f(unsigned short u) {
    unsigned int v = ((unsigned int)u) << 16;
    return __builtin_bit_cast(float, v);
}

// ---- prep: x (f32) -> xb (bf16) ----
__global__ void k_prep_x(const float* __restrict__ x, unsigned short* __restrict__ xb) {
    int i = (blockIdx.x * 256 + threadIdx.x) * 4;
    if (i >= NNODE * CIN) return;
    float4 v = *reinterpret_cast<const float4*>(x + i);
    ushort4 o;
    o.x = f2bf(v.x); o.y = f2bf(v.y); o.z = f2bf(v.z); o.w = f2bf(v.w);
    *reinterpret_cast<ushort4*>(xb + i) = o;
}

// ---- prep: W (f32 [8][64][64]) -> B-fragment-ordered bf16, k = r*64 + ki ----
// tile = kt*4+nt; lane l holds B[k = kt*32 + (l>>4)*8 + j][col = nt*16 + (l&15)], j=0..7
// W element for flat k: Wflat[k*64 + col]  (k = r*64+ki  ==  [r][ki] row-major)
__global__ void k_prep_w(const float* __restrict__ W, unsigned short* __restrict__ wf) {
    int tid = blockIdx.x * 256 + threadIdx.x;
    if (tid >= 64 * 64) return;
    int tile = tid >> 6;
    int lane = tid & 63;
    int kt = tile >> 2, nt = tile & 3;
    int kbase = kt * 32 + (lane >> 4) * 8;
    int col = nt * 16 + (lane & 15);
    unsigned short v[8];
#pragma unroll
    for (int j = 0; j < 8; ++j) {
        int k = kbase + j;                  // 0..511 == r*64 + ki
        v[j] = f2bf(W[k * 64 + col]);
    }
    ushort4* dst = reinterpret_cast<ushort4*>(wf + (size_t)tid * 8);
    ushort4 lo, hi;
    lo.x = v[0]; lo.y = v[1]; lo.z = v[2]; lo.w = v[3];
    hi.x = v[4]; hi.y = v[5]; hi.z = v[6]; hi.w = v[7];
    dst[0] = lo; dst[1] = hi;
}

// ---- main: block = 4 waves share one 16-node group ----
// Accumulate S[16][512] (f32, LDS, swizzled) via ds_add_f32: relation t only
// offsets the address -> no 8-way compare/select per edge. Each wave owns its
// 4 rows, so all same-address adds are within-wave serial (deterministic).
__launch_bounds__(256, 8)
__global__ void k_main(const unsigned short* __restrict__ xb,
                       const bf16x8* __restrict__ wf,
                       const int* __restrict__ ptr,
                       const int* __restrict__ idx,
                       const int* __restrict__ et,
                       const int* __restrict__ hmap,
                       const float* __restrict__ hbuf,
                       float* __restrict__ out) {
    __shared__ __align__(16) float Sf[16 * 512];   // 32 KB, byte ^= ((row&15)<<4)

    int wave = __builtin_amdgcn_readfirstlane((int)(threadIdx.x >> 6));
    int lane = threadIdx.x & 63;
    int n0 = blockIdx.x * 16;
    int nbase = n0 + wave * 4;
    char* sb = reinterpret_cast<char*>(&Sf[0]);

    // zero S (swizzle is row-internal, so linear zeroing is fine)
    {
        f32x4 z = {0.f, 0.f, 0.f, 0.f};
        f32x4* sz = reinterpret_cast<f32x4*>(sb);
#pragma unroll
        for (int i = 0; i < 8; ++i)
            sz[threadIdx.x + i * 256] = z;
    }
    __syncthreads();

    int eb0 = ptr[nbase + 0], eb1 = ptr[nbase + 1], eb2 = ptr[nbase + 2],
        eb3 = ptr[nbase + 3], eb4 = ptr[nbase + 4];
    bool fixed16 = (eb1 - eb0 == 16) && (eb2 - eb1 == 16) &&
                   (eb3 - eb2 == 16) && (eb4 - eb3 == 16);

    // per-node swizzled LDS base: row*2048 + (lane*4 ^ ((row&15)<<4))
    int vbase[4];
#pragma unroll
    for (int nn = 0; nn < 4; ++nn) {
        int row = wave * 4 + nn;
        vbase[nn] = row * 2048 + ((lane * 4) ^ ((row & 15) << 4));
    }

    if (fixed16) {
        // -------- fast path: 64 contiguous edges for this wave --------
        int vidx = idx[eb0 + lane];
        int vtyp = et[eb0 + lane];

        unsigned short xvA[16], xvB[16];

#define LOADN(buf, nn)                                                        \
        _Pragma("unroll")                                                     \
        for (int ee = 0; ee < 16; ++ee) {                                     \
            int src = __builtin_amdgcn_readlane(vidx, (nn) * 16 + ee);        \
            buf[ee] = xb[src * 64 + lane];                                    \
        }
#define ACCN(buf, nn)                                                         \
        _Pragma("unroll")                                                     \
        for (int ee = 0; ee < 16; ++ee) {                                     \
            int t = __builtin_amdgcn_readlane(vtyp, (nn) * 16 + ee);          \
            float v = bf2f(buf[ee]);                                          \
            atomicAdd(reinterpret_cast<float*>(sb + vbase[nn] + t * 256), v); \
        }

        LOADN(xvA, 0);
        LOADN(xvB, 1);
        ACCN(xvA, 0);
        LOADN(xvA, 2);
        ACCN(xvB, 1);
        LOADN(xvB, 3);
        ACCN(xvA, 2);
        ACCN(xvB, 3);
#undef LOADN
#undef ACCN
    } else {
        // -------- generic path --------
        int l16 = lane & 15;
        int ebs[5] = {eb0, eb1, eb2, eb3, eb4};
#pragma unroll
        for (int nn = 0; nn < 4; ++nn) {
            int eb = ebs[nn], en = ebs[nn + 1];
            for (int e = eb; e < en; e += 16) {
                int m = en - e; if (m > 16) m = 16;
                int vi = 0, vt = 0;
                if (l16 < m) { vi = idx[e + l16]; vt = et[e + l16]; }
                for (int ee = 0; ee < m; ++ee) {
                    int src = __builtin_amdgcn_readlane(vi, ee);
                    int t   = __builtin_amdgcn_readlane(vt, ee);
                    float v = bf2f(xb[src * 64 + lane]);
                    atomicAdd(reinterpret_cast<float*>(sb + vbase[nn] + t * 256), v);
                }
            }
        }
    }
    __syncthreads();

    // ---------- MFMA phase: wave handles N-slice nt = wave ----------
    // A-frag: S[row][kt*32 + hi*8 + j] (f32) -> bf16, row = lane&15, hi = lane>>4
    int nt = wave;
    f32x4 acc = {0.f,0.f,0.f,0.f};
    int arow = lane & 15;
    int ahi  = lane >> 4;
    int axor = arow << 4;                       // (row&15)<<4
    int abase = arow * 2048 + ahi * 32;
#pragma unroll 4
    for (int kt = 0; kt < 16; ++kt) {
        int b0 = (abase + kt * 128) ^ axor;
        int b1 = (abase + kt * 128 + 16) ^ axor;
        f32x4 lo = *reinterpret_cast<const f32x4*>(sb + b0);
        f32x4 hi = *reinterpret_cast<const f32x4*>(sb + b1);
        bf16x8 a;
#pragma unroll
        for (int j = 0; j < 4; ++j) {
            a[j]     = (short)f2bf(lo[j]);
            a[4 + j] = (short)f2bf(hi[j]);
        }
        bf16x8 b = wf[(kt * 4 + nt) * 64 + lane];
        acc = __builtin_amdgcn_mfma_f32_16x16x32_bf16(a, b, acc, 0, 0, 0);
    }

    // ---------- epilogue: /deg, history overwrite, write both outputs ----------
    int col   = nt * 16 + (lane & 15);
    int rquad = (lane >> 4) * 4;
#pragma unroll
    for (int j = 0; j < 4; ++j) {
        int node = n0 + rquad + j;
        float invd = 1.0f / (float)(ptr[node + 1] - ptr[node]);
        float v = acc[j] * invd;
        if (hmap[node] != -1) v = hbuf[node * 64 + col];
        out[node * 64 + col] = v;
        out[NNODE * 64 + node * 64 + col] = v;
    }
}

extern "C" void kernel_launch(void* const* d_in, const int* in_sizes, int n_in,
                              void* d_out, int out_size, void* d_ws, size_t ws_size,
                              hipStream_t stream) {
    (void)in_sizes; (void)n_in; (void)out_size; (void)ws_size;
    const float* x    = (const float*)d_in[0];
    const float* W    = (const float*)d_in[1];
    const int*   ptr  = (const int*)d_in[2];
    const int*   idx  = (const int*)d_in[3];
    const int*   et   = (const int*)d_in[4];
    const int*   hmap = (const int*)d_in[6];
    const float* hbuf = (const float*)d_in[7];
    float* out = (float*)d_out;

    unsigned short* xb = (unsigned short*)d_ws;                                     // 12.8 MB
    unsigned short* wfu = (unsigned short*)((char*)d_ws + (size_t)NNODE * CIN * 2); // 64 KB

    k_prep_x<<<dim3((NNODE * CIN / 4 + 255) / 256), dim3(256), 0, stream>>>(x, xb);
    k_prep_w<<<dim3(16), dim3(256), 0, stream>>>(W, wfu);
    k_main<<<dim3(NGRP), dim3(256), 0, stream>>>(
        xb, (const bf16x8*)wfu, ptr, idx, et, hmap, hbuf, out);
}

// Round 6
// 100.429 us; speedup vs baseline: 5.4416x; 5.4416x over previous
//
#include <hip/hip_runtime.h>
#include <hip/hip_bf16.h>

#define NNODE 100000
#define CIN   64
#define CHID  64
#define NREL  8
#define NGRP  6250

typedef __attribute__((ext_vector_type(8))) short bf16x8;
typedef __attribute__((ext_vector_type(4))) float f32x4;

__device__ __forceinline__ unsigned short f2bf(float f) {
    __hip_bfloat16 h = __float2bfloat16(f);
    return __builtin_bit_cast(unsigned short, h);
}
__device__ __forceinline__ float bf2f(unsigned short u) {
    unsigned int v = ((unsigned int)u) << 16;
    return __builtin_bit_cast(float, v);
}

// =====================  NEW PATH: xr = x @ W[r], then pure gather-add =====================
// xr layout: [r][node][ch] bf16, 8*100000*64*2 = 102,400,000 bytes in d_ws.

// ---- prep W -> B-fragment order for k_xr. GEMM is [M=100k, K=64] @ [K=64, N=512],
// N = r*64 + ch. tile = kt*32 + nt (kt 0..1, nt 0..31); lane l holds
// B[k = kt*32 + (l>>4)*8 + j][col = nt*16 + (l&15)], j=0..7; W elem = W[col>>6][k][col&63].
__global__ void k_prep_w_xr(const float* __restrict__ W, unsigned short* __restrict__ wf) {
    int tid = blockIdx.x * 256 + threadIdx.x;
    if (tid >= 64 * 64) return;
    int tile = tid >> 6, lane = tid & 63;
    int kt = tile >> 5, nt = tile & 31;
    int kbase = kt * 32 + (lane >> 4) * 8;
    int col = nt * 16 + (lane & 15);
    int r = col >> 6, ch = col & 63;
    unsigned short v[8];
#pragma unroll
    for (int j = 0; j < 8; ++j)
        v[j] = f2bf(W[r * 4096 + (kbase + j) * 64 + ch]);
    ushort4* dst = reinterpret_cast<ushort4*>(wf + (size_t)tid * 8);
    ushort4 lo, hi;
    lo.x = v[0]; lo.y = v[1]; lo.z = v[2]; lo.w = v[3];
    hi.x = v[4]; hi.y = v[5]; hi.z = v[6]; hi.w = v[7];
    dst[0] = lo; dst[1] = hi;
}

// ---- k_xr: block = 16 nodes, 4 waves; wave w covers N-cols [w*128, w*128+128).
__launch_bounds__(256, 4)
__global__ void k_xr(const float* __restrict__ x, const bf16x8* __restrict__ wf,
                     unsigned short* __restrict__ xr) {
    int wave = __builtin_amdgcn_readfirstlane((int)(threadIdx.x >> 6));
    int lane = threadIdx.x & 63;
    int n0 = blockIdx.x * 16;
    int arow = lane & 15, ahi = lane >> 4;

    // A-frags direct from x (f32 -> bf16): A[row = arow][k = kt*32 + ahi*8 + j]
    const float* xp = x + (size_t)(n0 + arow) * 64 + ahi * 8;
    bf16x8 a[2];
#pragma unroll
    for (int kt = 0; kt < 2; ++kt) {
        float4 lo = *reinterpret_cast<const float4*>(xp + kt * 32);
        float4 hi = *reinterpret_cast<const float4*>(xp + kt * 32 + 4);
        bf16x8 t;
        t[0]=(short)f2bf(lo.x); t[1]=(short)f2bf(lo.y); t[2]=(short)f2bf(lo.z); t[3]=(short)f2bf(lo.w);
        t[4]=(short)f2bf(hi.x); t[5]=(short)f2bf(hi.y); t[6]=(short)f2bf(hi.z); t[7]=(short)f2bf(hi.w);
        a[kt] = t;
    }

    f32x4 acc[8] = {{0.f,0.f,0.f,0.f},{0.f,0.f,0.f,0.f},{0.f,0.f,0.f,0.f},{0.f,0.f,0.f,0.f},
                    {0.f,0.f,0.f,0.f},{0.f,0.f,0.f,0.f},{0.f,0.f,0.f,0.f},{0.f,0.f,0.f,0.f}};
#pragma unroll
    for (int kt = 0; kt < 2; ++kt) {
#pragma unroll
        for (int t = 0; t < 8; ++t) {
            bf16x8 b = wf[(kt * 32 + wave * 8 + t) * 64 + lane];
            acc[t] = __builtin_amdgcn_mfma_f32_16x16x32_bf16(a[kt], b, acc[t], 0, 0, 0);
        }
    }

    // epilogue: C row=(lane>>4)*4+j (node), col=lane&15 within tile
#pragma unroll
    for (int t = 0; t < 8; ++t) {
        int nt = wave * 8 + t;
        int col = nt * 16 + arow;
        int r = col >> 6, ch = col & 63;
        unsigned short* dst = xr + ((size_t)r * NNODE + n0 + ahi * 4) * 64 + ch;
#pragma unroll
        for (int j = 0; j < 4; ++j)
            dst[(size_t)j * 64] = f2bf(acc[t][j]);
    }
}

// ---- k_gather: wave handles 4 nodes; per edge: one ushort row-gather + add.
__launch_bounds__(256, 8)
__global__ void k_gather(const unsigned short* __restrict__ xr,
                         const int* __restrict__ ptr,
                         const int* __restrict__ idx,
                         const int* __restrict__ et,
                         const int* __restrict__ hmap,
                         const float* __restrict__ hbuf,
                         float* __restrict__ out) {
    int wave = __builtin_amdgcn_readfirstlane((int)(threadIdx.x >> 6));
    int lane = threadIdx.x & 63;
    int n0 = (blockIdx.x * 4 + wave) * 4;

    int e0 = ptr[n0], e1 = ptr[n0 + 1], e2 = ptr[n0 + 2], e3 = ptr[n0 + 3], e4 = ptr[n0 + 4];
    bool fixed16 = (e1 - e0 == 16) && (e2 - e1 == 16) && (e3 - e2 == 16) && (e4 - e3 == 16);

    float vres[4];

    if (fixed16) {
        int vidx = idx[e0 + lane];
        int vtyp = et[e0 + lane];
        int ci = vtyp * NNODE + vidx;          // combined row id, all 64 edges at once

        unsigned short gA[16], gB[16];

#define GLOAD(buf, nn)                                                        \
        _Pragma("unroll")                                                     \
        for (int ee = 0; ee < 16; ++ee) {                                     \
            int row = __builtin_amdgcn_readlane(ci, (nn) * 16 + ee);          \
            buf[ee] = xr[row * 64 + lane];                                    \
        }
#define GACC(buf, nn)                                                         \
        {                                                                     \
            float p0 = 0.f, p1 = 0.f, p2 = 0.f, p3 = 0.f;                     \
            _Pragma("unroll")                                                 \
            for (int ee = 0; ee < 16; ee += 4) {                              \
                p0 += bf2f(buf[ee]); p1 += bf2f(buf[ee + 1]);                 \
                p2 += bf2f(buf[ee + 2]); p3 += bf2f(buf[ee + 3]);             \
            }                                                                 \
            vres[nn] = ((p0 + p1) + (p2 + p3)) * 0.0625f;                     \
        }

        GLOAD(gA, 0);
        GLOAD(gB, 1);
        GACC(gA, 0);
        GLOAD(gA, 2);
        GACC(gB, 1);
        GLOAD(gB, 3);
        GACC(gA, 2);
        GACC(gB, 3);
#undef GLOAD
#undef GACC
    } else {
        int ebs[5] = {e0, e1, e2, e3, e4};
        for (int nn = 0; nn < 4; ++nn) {
            float s = 0.f;
            for (int e = ebs[nn]; e < ebs[nn + 1]; ++e) {
                int row = et[e] * NNODE + idx[e];          // scalar loads (uniform)
                s += bf2f(xr[row * 64 + lane]);
            }
            int deg = ebs[nn + 1] - ebs[nn];
            vres[nn] = s / (float)(deg > 0 ? deg : 1);
        }
    }

#pragma unroll
    for (int nn = 0; nn < 4; ++nn) {
        int node = n0 + nn;
        float v = vres[nn];
        if (hmap[node] != -1) v = hbuf[node * 64 + lane];
        out[(size_t)node * 64 + lane] = v;
        out[(size_t)NNODE * 64 + (size_t)node * 64 + lane] = v;
    }
}

// =====================  FALLBACK PATH (R3, 88 us) — used if ws_size too small ==============
__global__ void k_prep_x(const float* __restrict__ x, unsigned short* __restrict__ xb) {
    int i = (blockIdx.x * 256 + threadIdx.x) * 4;
    if (i >= NNODE * CIN) return;
    float4 v = *reinterpret_cast<const float4*>(x + i);
    ushort4 o;
    o.x = f2bf(v.x); o.y = f2bf(v.y); o.z = f2bf(v.z); o.w = f2bf(v.w);
    *reinterpret_cast<ushort4*>(xb + i) = o;
}

__global__ void k_prep_w_fb(const float* __restrict__ W, unsigned short* __restrict__ wf) {
    int tid = blockIdx.x * 256 + threadIdx.x;
    if (tid >= 64 * 64) return;
    int tile = tid >> 6, lane = tid & 63;
    int kt = tile >> 2, nt = tile & 3;
    int kbase = kt * 32 + (lane >> 4) * 8;
    int col = nt * 16 + (lane & 15);
    unsigned short v[8];
#pragma unroll
    for (int j = 0; j < 8; ++j) {
        int k = kbase + j;
        int r = k & 7, ki = k >> 3;
        v[j] = f2bf(W[r * 4096 + ki * 64 + col]);
    }
    ushort4* dst = reinterpret_cast<ushort4*>(wf + (size_t)tid * 8);
    ushort4 lo, hi;
    lo.x = v[0]; lo.y = v[1]; lo.z = v[2]; lo.w = v[3];
    hi.x = v[4]; hi.y = v[5]; hi.z = v[6]; hi.w = v[7];
    dst[0] = lo; dst[1] = hi;
}

__launch_bounds__(256, 8)
__global__ void k_main_fb(const unsigned short* __restrict__ xb,
                          const bf16x8* __restrict__ wf,
                          const int* __restrict__ ptr,
                          const int* __restrict__ idx,
                          const int* __restrict__ et,
                          const int* __restrict__ hmap,
                          const float* __restrict__ hbuf,
                          float* __restrict__ out) {
    __shared__ __align__(16) unsigned short S[8192];
    int wave = __builtin_amdgcn_readfirstlane((int)(threadIdx.x >> 6));
    int lane = threadIdx.x & 63;
    int n0 = blockIdx.x * 16;
    int nbase = n0 + wave * 4;
    char* sb = reinterpret_cast<char*>(&S[0]);
    int eb0 = ptr[nbase + 0], eb1 = ptr[nbase + 1], eb2 = ptr[nbase + 2],
        eb3 = ptr[nbase + 3], eb4 = ptr[nbase + 4];
    bool fixed16 = (eb1 - eb0 == 16) && (eb2 - eb1 == 16) &&
                   (eb3 - eb2 == 16) && (eb4 - eb3 == 16);
    float sums[4][8];
    if (fixed16) {
        int vidx = idx[eb0 + lane];
        int vtyp = et[eb0 + lane];
        unsigned short xvA[16], xvB[16];
#define LOADN(buf, nn)                                                        \
        _Pragma("unroll")                                                     \
        for (int ee = 0; ee < 16; ++ee) {                                     \
            int src = __builtin_amdgcn_readlane(vidx, (nn) * 16 + ee);        \
            buf[ee] = xb[src * 64 + lane];                                    \
        }
#define ACCN(buf, nn)                                                         \
        {                                                                     \
            float s0=0.f,s1=0.f,s2=0.f,s3=0.f,s4=0.f,s5=0.f,s6=0.f,s7=0.f;    \
            _Pragma("unroll")                                                 \
            for (int ee = 0; ee < 16; ++ee) {                                 \
                int t = __builtin_amdgcn_readlane(vtyp, (nn) * 16 + ee);      \
                float v = bf2f(buf[ee]);                                      \
                if      (t == 0) s0 += v;                                     \
                else if (t == 1) s1 += v;                                     \
                else if (t == 2) s2 += v;                                     \
                else if (t == 3) s3 += v;                                     \
                else if (t == 4) s4 += v;                                     \
                else if (t == 5) s5 += v;                                     \
                else if (t == 6) s6 += v;                                     \
                else             s7 += v;                                     \
            }                                                                 \
            sums[nn][0]=s0; sums[nn][1]=s1; sums[nn][2]=s2; sums[nn][3]=s3;   \
            sums[nn][4]=s4; sums[nn][5]=s5; sums[nn][6]=s6; sums[nn][7]=s7;   \
        }
        LOADN(xvA, 0); LOADN(xvB, 1); ACCN(xvA, 0); LOADN(xvA, 2);
        ACCN(xvB, 1); LOADN(xvB, 3); ACCN(xvA, 2); ACCN(xvB, 3);
#undef LOADN
#undef ACCN
    } else {
        int l16 = lane & 15;
        int ebs[5] = {eb0, eb1, eb2, eb3, eb4};
        for (int nn = 0; nn < 4; ++nn) {
            int eb = ebs[nn], en = ebs[nn + 1];
            float s0=0.f,s1=0.f,s2=0.f,s3=0.f,s4=0.f,s5=0.f,s6=0.f,s7=0.f;
            for (int e = eb; e < en; e += 16) {
                int m = en - e; if (m > 16) m = 16;
                int vi = 0, vt = 0;
                if (l16 < m) { vi = idx[e + l16]; vt = et[e + l16]; }
                for (int ee = 0; ee < m; ++ee) {
                    int src = __builtin_amdgcn_readlane(vi, ee);
                    int t   = __builtin_amdgcn_readlane(vt, ee);
                    float v = bf2f(xb[src * 64 + lane]);
                    if      (t == 0) s0 += v;
                    else if (t == 1) s1 += v;
                    else if (t == 2) s2 += v;
                    else if (t == 3) s3 += v;
                    else if (t == 4) s4 += v;
                    else if (t == 5) s5 += v;
                    else if (t == 6) s6 += v;
                    else             s7 += v;
                }
            }
            sums[nn][0]=s0; sums[nn][1]=s1; sums[nn][2]=s2; sums[nn][3]=s3;
            sums[nn][4]=s4; sums[nn][5]=s5; sums[nn][6]=s6; sums[nn][7]=s7;
        }
    }
#pragma unroll
    for (int nn = 0; nn < 4; ++nn) {
        int row = wave * 4 + nn;
        bf16x8 pk;
#pragma unroll
        for (int r = 0; r < 8; ++r) pk[r] = (short)f2bf(sums[nn][r]);
        unsigned int byte = ((unsigned int)row * 1024u + (unsigned int)lane * 16u)
                            ^ (((unsigned int)(row & 7)) << 4);
        *reinterpret_cast<bf16x8*>(sb + byte) = pk;
    }
    __syncthreads();
    int nt = wave;
    f32x4 acc = {0.f,0.f,0.f,0.f};
    unsigned int arow  = (unsigned int)(lane & 15);
    unsigned int abase = arow * 1024u + (unsigned int)((lane >> 4) * 16);
    unsigned int axor  = (arow & 7u) << 4;
#pragma unroll 4
    for (int kt = 0; kt < 16; ++kt) {
        unsigned int abyte = (abase + (unsigned int)kt * 64u) ^ axor;
        bf16x8 a = *reinterpret_cast<const bf16x8*>(sb + abyte);
        bf16x8 b = wf[(kt * 4 + nt) * 64 + lane];
        acc = __builtin_amdgcn_mfma_f32_16x16x32_bf16(a, b, acc, 0, 0, 0);
    }
    int col   = nt * 16 + (lane & 15);
    int rquad = (lane >> 4) * 4;
#pragma unroll
    for (int j = 0; j < 4; ++j) {
        int node = n0 + rquad + j;
        float invd = 1.0f / (float)(ptr[node + 1] - ptr[node]);
        float v = acc[j] * invd;
        if (hmap[node] != -1) v = hbuf[node * 64 + col];
        out[node * 64 + col] = v;
        out[NNODE * 64 + node * 64 + col] = v;
    }
}

// =========================================================================================
extern "C" void kernel_launch(void* const* d_in, const int* in_sizes, int n_in,
                              void* d_out, int out_size, void* d_ws, size_t ws_size,
                              hipStream_t stream) {
    (void)in_sizes; (void)n_in; (void)out_size;
    const float* x    = (const float*)d_in[0];
    const float* W    = (const float*)d_in[1];
    const int*   ptr  = (const int*)d_in[2];
    const int*   idx  = (const int*)d_in[3];
    const int*   et   = (const int*)d_in[4];
    const int*   hmap = (const int*)d_in[6];
    const float* hbuf = (const float*)d_in[7];
    float* out = (float*)d_out;

    const size_t XR_BYTES = (size_t)NREL * NNODE * 64 * 2;   // 102,400,000
    const size_t WF_BYTES = 64 * 64 * 8 * 2;                 // 65,536

    if (ws_size >= XR_BYTES + WF_BYTES) {
        unsigned short* xr = (unsigned short*)d_ws;
        unsigned short* wf = (unsigned short*)((char*)d_ws + XR_BYTES);
        k_prep_w_xr<<<dim3(16), dim3(256), 0, stream>>>(W, wf);
        k_xr<<<dim3(NGRP), dim3(256), 0, stream>>>(x, (const bf16x8*)wf, xr);
        k_gather<<<dim3(NGRP), dim3(256), 0, stream>>>(xr, ptr, idx, et, hmap, hbuf, out);
    } else {
        unsigned short* xb = (unsigned short*)d_ws;
        unsigned short* wf = (unsigned short*)((char*)d_ws + (size_t)NNODE * CIN * 2);
        k_prep_x<<<dim3((NNODE * CIN / 4 + 255) / 256), dim3(256), 0, stream>>>(x, xb);
        k_prep_w_fb<<<dim3(16), dim3(256), 0, stream>>>(W, wf);
        k_main_fb<<<dim3(NGRP), dim3(256), 0, stream>>>(
            xb, (const bf16x8*)wf, ptr, idx, et, hmap, hbuf, out);
    }
}

// Round 7
// 70.004 us; speedup vs baseline: 7.8066x; 1.4346x over previous
//
#include <hip/hip_runtime.h>
#include <hip/hip_bf16.h>

#define NNODE 100000
#define CIN   64
#define CHID  64
#define NREL  8
#define NGRP  6250     // NNODE / 16

typedef __attribute__((ext_vector_type(8))) short bf16x8;
typedef __attribute__((ext_vector_type(4))) float f32x4;
typedef unsigned long long u64;

__device__ __forceinline__ unsigned short f2bf(float f) {
    __hip_bfloat16 h = __float2bfloat16(f);
    return __builtin_bit_cast(unsigned short, h);
}
__device__ __forceinline__ float bf2f(unsigned short u) {
    unsigned int v = ((unsigned int)u) << 16;
    return __builtin_bit_cast(float, v);
}

// ---- prep: x (f32) -> xb (bf16) ----
__global__ void k_prep_x(const float* __restrict__ x, unsigned short* __restrict__ xb) {
    int i = (blockIdx.x * 256 + threadIdx.x) * 4;
    if (i >= NNODE * CIN) return;
    float4 v = *reinterpret_cast<const float4*>(x + i);
    ushort4 o;
    o.x = f2bf(v.x); o.y = f2bf(v.y); o.z = f2bf(v.z); o.w = f2bf(v.w);
    *reinterpret_cast<ushort4*>(xb + i) = o;
}

// ---- prep: per-node counting sort of edges by type (deg==16 fast case) ----
// outputs: sidx[e] = source node of sorted edge, typ4[node] = 16x4-bit types in sorted order.
__global__ void k_sort(const int* __restrict__ ptr, const int* __restrict__ idx,
                       const int* __restrict__ et, int* __restrict__ sidx,
                       u64* __restrict__ typ4) {
    int node = blockIdx.x * 256 + threadIdx.x;
    if (node >= NNODE) return;
    int eb = ptr[node], en = ptr[node + 1];
    if (en - eb != 16) { typ4[node] = 0; return; }   // generic path ignores these
    u64 cnt = 0;
#pragma unroll
    for (int ee = 0; ee < 16; ++ee)
        cnt += 1ull << (8 * et[eb + ee]);
    // exclusive byte-wise prefix sums (sums <= 16, no carries)
    u64 pre = cnt * 0x0101010101010100ull;
    u64 occ = 0, tp = 0;
#pragma unroll
    for (int ee = 0; ee < 16; ++ee) {
        int te = et[eb + ee];
        int sh = te * 8;
        int pos = (int)((pre >> sh) & 0xFF) + (int)((occ >> sh) & 0xFF);
        occ += 1ull << sh;
        sidx[eb + pos] = idx[eb + ee];
        tp |= (u64)te << (4 * pos);
    }
    typ4[node] = tp;
}

// ---- prep: W (f32 [8][64][64]) -> B-fragment-ordered bf16, flat k = r*64 + ki ----
// tile = kt*4+nt; lane l holds B[k = kt*32 + (l>>4)*8 + j][col = nt*16 + (l&15)], j=0..7
// W element for flat k: Wflat[k*64 + col]  (k = r*64+ki == [r][ki] row-major)
__global__ void k_prep_w(const float* __restrict__ W, unsigned short* __restrict__ wf) {
    int tid = blockIdx.x * 256 + threadIdx.x;
    if (tid >= 64 * 64) return;
    int tile = tid >> 6, lane = tid & 63;
    int kt = tile >> 2, nt = tile & 3;
    int kbase = kt * 32 + (lane >> 4) * 8;
    int col = nt * 16 + (lane & 15);
    unsigned short v[8];
#pragma unroll
    for (int j = 0; j < 8; ++j)
        v[j] = f2bf(W[(kbase + j) * 64 + col]);
    ushort4* dst = reinterpret_cast<ushort4*>(wf + (size_t)tid * 8);
    ushort4 lo, hi;
    lo.x = v[0]; lo.y = v[1]; lo.z = v[2]; lo.w = v[3];
    hi.x = v[4]; hi.y = v[5]; hi.z = v[6]; hi.w = v[7];
    dst[0] = lo; dst[1] = hi;
}

// ---- main: block = 4 waves share one 16-node group; S[16][512] bf16 swizzled ----
// Fast path: staged 16-deep gather (ping-pong) over SORTED edges; accumulate a single
// running sum; at wave-uniform run boundaries (from typ4 nibbles) one ds_write_b16 to
// S[row][t*64 + lane]. Relation dispatch cost ~0 per edge.
__launch_bounds__(256, 8)
__global__ void k_main(const unsigned short* __restrict__ xb,
                       const bf16x8* __restrict__ wf,
                       const int* __restrict__ ptr,
                       const int* __restrict__ sidx,
                       const u64* __restrict__ typ4,
                       const int* __restrict__ idx,
                       const int* __restrict__ et,
                       const int* __restrict__ hmap,
                       const float* __restrict__ hbuf,
                       float* __restrict__ out) {
    __shared__ __align__(16) unsigned short S[8192];   // 16 rows x 512 k, 16 KB

    int wave = __builtin_amdgcn_readfirstlane((int)(threadIdx.x >> 6));
    int lane = threadIdx.x & 63;
    int n0 = blockIdx.x * 16;
    int nbase = n0 + wave * 4;
    char* sb = reinterpret_cast<char*>(&S[0]);

    // zero S (all types absent must read as 0)
    {
        f32x4 z = {0.f, 0.f, 0.f, 0.f};
        f32x4* sz = reinterpret_cast<f32x4*>(sb);
        sz[threadIdx.x]       = z;
        sz[threadIdx.x + 256] = z;
        sz[threadIdx.x + 512] = z;
        sz[threadIdx.x + 768] = z;
    }
    __syncthreads();

    int eb0 = ptr[nbase + 0], eb1 = ptr[nbase + 1], eb2 = ptr[nbase + 2],
        eb3 = ptr[nbase + 3], eb4 = ptr[nbase + 4];
    bool fixed16 = (eb1 - eb0 == 16) && (eb2 - eb1 == 16) &&
                   (eb3 - eb2 == 16) && (eb4 - eb3 == 16);

    if (fixed16) {
        int vsrc = sidx[eb0 + lane];           // 64 sorted sources for this wave
        u64 tp0 = typ4[nbase + 0], tp1 = typ4[nbase + 1],
            tp2 = typ4[nbase + 2], tp3 = typ4[nbase + 3];

        unsigned short xvA[16], xvB[16];

#define LOADN(buf, nn)                                                        \
        _Pragma("unroll")                                                     \
        for (int ee = 0; ee < 16; ++ee) {                                     \
            int src = __builtin_amdgcn_readlane(vsrc, (nn) * 16 + ee);        \
            buf[ee] = xb[src * 64 + lane];                                    \
        }
// run-boundary flush accumulate: branches are wave-uniform (tp is scalar)
#define FLUSHACC(buf, nn, tp)                                                 \
        {                                                                     \
            int row_ = wave * 4 + (nn);                                       \
            unsigned int vlx_ = ((unsigned int)lane * 2u)                     \
                                ^ (((unsigned int)(row_ & 7)) << 4);          \
            unsigned int rb_ = (unsigned int)row_ * 1024u;                    \
            float s_ = 0.f;                                                   \
            _Pragma("unroll")                                                 \
            for (int ee = 0; ee < 16; ++ee) {                                 \
                s_ += bf2f(buf[ee]);                                          \
                int tcur_ = (int)((tp >> (4 * ee)) & 0xF);                    \
                int tnxt_ = (ee == 15) ? 16 : (int)((tp >> (4 * ee + 4)) & 0xF); \
                if (tcur_ != tnxt_) {                                         \
                    unsigned int byte_ = rb_ + (unsigned int)tcur_ * 128u + vlx_; \
                    *reinterpret_cast<unsigned short*>(sb + byte_) = f2bf(s_); \
                    s_ = 0.f;                                                 \
                }                                                             \
            }                                                                 \
        }

        LOADN(xvA, 0);
        LOADN(xvB, 1);
        FLUSHACC(xvA, 0, tp0);
        LOADN(xvA, 2);
        FLUSHACC(xvB, 1, tp1);
        LOADN(xvB, 3);
        FLUSHACC(xvA, 2, tp2);
        FLUSHACC(xvB, 3, tp3);
#undef LOADN
#undef FLUSHACC
    } else {
        // -------- generic path: unsorted, 8-register dispatch --------
        int l16 = lane & 15;
        int ebs[5] = {eb0, eb1, eb2, eb3, eb4};
        for (int nn = 0; nn < 4; ++nn) {
            int eb = ebs[nn], en = ebs[nn + 1];
            float s0=0.f,s1=0.f,s2=0.f,s3=0.f,s4=0.f,s5=0.f,s6=0.f,s7=0.f;
            for (int e = eb; e < en; e += 16) {
                int m = en - e; if (m > 16) m = 16;
                int vi = 0, vt = 0;
                if (l16 < m) { vi = idx[e + l16]; vt = et[e + l16]; }
                for (int ee = 0; ee < m; ++ee) {
                    int src = __builtin_amdgcn_readlane(vi, ee);
                    int t   = __builtin_amdgcn_readlane(vt, ee);
                    float v = bf2f(xb[src * 64 + lane]);
                    if      (t == 0) s0 += v;
                    else if (t == 1) s1 += v;
                    else if (t == 2) s2 += v;
                    else if (t == 3) s3 += v;
                    else if (t == 4) s4 += v;
                    else if (t == 5) s5 += v;
                    else if (t == 6) s6 += v;
                    else             s7 += v;
                }
            }
            int row = wave * 4 + nn;
            unsigned int vlx = ((unsigned int)lane * 2u)
                               ^ (((unsigned int)(row & 7)) << 4);
            unsigned int rb = (unsigned int)row * 1024u;
            float sv[8] = {s0,s1,s2,s3,s4,s5,s6,s7};
#pragma unroll
            for (int r = 0; r < 8; ++r) {
                unsigned int byte = rb + (unsigned int)r * 128u + vlx;
                *reinterpret_cast<unsigned short*>(sb + byte) = f2bf(sv[r]);
            }
        }
    }
    __syncthreads();

    // ---------- MFMA phase: wave handles N-slice nt = wave ----------
    int nt = wave;
    f32x4 acc = {0.f,0.f,0.f,0.f};
    unsigned int arow  = (unsigned int)(lane & 15);
    unsigned int abase = arow * 1024u + (unsigned int)((lane >> 4) * 16);
    unsigned int axor  = (arow & 7u) << 4;
#pragma unroll 4
    for (int kt = 0; kt < 16; ++kt) {
        unsigned int abyte = (abase + (unsigned int)kt * 64u) ^ axor;
        bf16x8 a = *reinterpret_cast<const bf16x8*>(sb + abyte);
        bf16x8 b = wf[(kt * 4 + nt) * 64 + lane];
        acc = __builtin_amdgcn_mfma_f32_16x16x32_bf16(a, b, acc, 0, 0, 0);
    }

    // ---------- epilogue: /deg, history overwrite, write both outputs ----------
    int col   = nt * 16 + (lane & 15);
    int rquad = (lane >> 4) * 4;
#pragma unroll
    for (int j = 0; j < 4; ++j) {
        int node = n0 + rquad + j;
        float invd = 1.0f / (float)(ptr[node + 1] - ptr[node]);
        float v = acc[j] * invd;
        if (hmap[node] != -1) v = hbuf[node * 64 + col];
        out[node * 64 + col] = v;
        out[NNODE * 64 + node * 64 + col] = v;
    }
}

extern "C" void kernel_launch(void* const* d_in, const int* in_sizes, int n_in,
                              void* d_out, int out_size, void* d_ws, size_t ws_size,
                              hipStream_t stream) {
    (void)in_sizes; (void)n_in; (void)out_size; (void)ws_size;
    const float* x    = (const float*)d_in[0];
    const float* W    = (const float*)d_in[1];
    const int*   ptr  = (const int*)d_in[2];
    const int*   idx  = (const int*)d_in[3];
    const int*   et   = (const int*)d_in[4];
    const int*   hmap = (const int*)d_in[6];
    const float* hbuf = (const float*)d_in[7];
    float* out = (float*)d_out;

    // workspace layout (all 16B-aligned): xb 12.8MB | wf 64KB | sidx 6.4MB | typ4 800KB
    char* w = (char*)d_ws;
    unsigned short* xb  = (unsigned short*)w;                      // 12,800,000 B
    unsigned short* wfu = (unsigned short*)(w + 12800000);         //     65,536 B
    int*            sidx= (int*)(w + 12865536);                    //  6,400,000 B
    u64*            tp4 = (u64*)(w + 19265536);                    //    800,000 B

    k_prep_x<<<dim3((NNODE * CIN / 4 + 255) / 256), dim3(256), 0, stream>>>(x, xb);
    k_sort<<<dim3((NNODE + 255) / 256), dim3(256), 0, stream>>>(ptr, idx, et, sidx, tp4);
    k_prep_w<<<dim3(16), dim3(256), 0, stream>>>(W, wfu);
    k_main<<<dim3(NGRP), dim3(256), 0, stream>>>(
        xb, (const bf16x8*)wfu, ptr, sidx, tp4, idx, et, hmap, hbuf, out);
}